// Round 3
// baseline (23.926 us; speedup 1.0000x reference)
//
#include <hip/hip_runtime.h>

#define PLACEHOLDER (-1)
#define KB 8   // blocks per heavy scan row

__device__ __forceinline__ void comb(float& v, int& i, float v2, int i2) {
    // argmax combine, numpy tie-break: lower index wins on equal value
    if (v2 > v || (v2 == v && i2 < i)) { v = v2; i = i2; }
}

// block-wide argmax (blockDim.x multiple of 64, <=1024); result broadcast to all
__device__ __forceinline__ void block_argmax(float& bv, int& bi, float* s_v, int* s_i) {
    #pragma unroll
    for (int off = 32; off > 0; off >>= 1) {
        float v2 = __shfl_down(bv, off);
        int   i2 = __shfl_down(bi, off);
        comb(bv, bi, v2, i2);
    }
    const int tid = threadIdx.x;
    const int nw  = blockDim.x >> 6;
    if ((tid & 63) == 0) { s_v[tid >> 6] = bv; s_i[tid >> 6] = bi; }
    __syncthreads();
    if (tid == 0) {
        for (int w = 1; w < nw; ++w) comb(bv, bi, s_v[w], s_i[w]);
        s_v[0] = bv; s_i[0] = bi;
    }
    __syncthreads();
    bv = s_v[0]; bi = s_i[0];
    __syncthreads();
}

// is_greedy may arrive as 1-byte bools, int32, or float32 — detect from content
__device__ __forceinline__ bool detect_greedy(const void* grd, int b, int B, int* s_flags) {
    const int tid = threadIdx.x;
    if (tid < 2) s_flags[tid] = 0;
    __syncthreads();
    const unsigned char* gb = (const unsigned char*)grd;
    for (int t = tid; t < B; t += blockDim.x) {
        unsigned char c = gb[t];
        if (c > 1) s_flags[0] = 1;          // bytes beyond {0,1} -> f32 payload
        if ((t & 3) && c) s_flags[1] = 1;   // nonzero off-word byte -> byte bools
    }
    __syncthreads();
    bool g;
    if (s_flags[0])      g = (((const float*)grd)[b] != 0.0f);
    else if (s_flags[1]) g = (gb[b] != 0);
    else                 g = (((const int*)grd)[b] != 0);
    return g;
}

__device__ __forceinline__ unsigned long long pack_vi(float v, int i) {
    return ((unsigned long long)__float_as_uint(v) << 32)
         | (unsigned long long)(0xFFFFFFFFu - (unsigned)i);
}

// K1: parallel gathers, accept bits, first-reject; writes all cheap outputs,
// emits one heavy-scan descriptor per request.
__global__ __launch_bounds__(64) void k1_prepass(
    const float* __restrict__ dp, const float* __restrict__ tp,
    const float* __restrict__ up, const int* __restrict__ cu,
    const int* __restrict__ did, const int* __restrict__ bonus,
    const void* __restrict__ grd, int* __restrict__ out,
    int* __restrict__ scanrow, int* __restrict__ scankind,
    unsigned long long* __restrict__ packed, int B, int V, int S)
{
    __shared__ int s_flags[2];
    const int b = blockIdx.x, tid = threadIdx.x;
    const bool g = detect_greedy(grd, b, B, s_flags);
    const int start = b ? cu[b - 1] : 0;
    const int len   = cu[b] - start;

    bool acc = true;
    if (tid < len) {
        const int i  = start + tid;
        const int td = did[i];
        const float dat = dp[(size_t)i * V + td];
        const float tat = tp[(size_t)i * V + td];
        acc = (dat > 0.0f && tat >= up[i] * dat);
    }
    const unsigned long long rej =
        (~__ballot(acc)) & ((len >= 64) ? ~0ull : ((1ull << len) - 1ull));

    if (tid == 0) {
        packed[b] = 0xFFFFFFFFull;   // (value=0, index=0) sentinel
        int* row = out + b * (S + 1);
        if (g) {
            scanrow[b] = start; scankind[b] = 1;   // K4 writes everything
        } else {
            const int fr = rej ? (__ffsll((long long)rej) - 1) : len;
            for (int p = 0; p < fr; ++p) row[p] = did[start + p];
            if (fr < len) {
                scanrow[b] = start + fr; scankind[b] = 0;   // K4 fills row[fr]
                for (int p = fr + 1; p <= S; ++p) row[p] = PLACEHOLDER;
            } else {
                scanrow[b] = -1; scankind[b] = 0;
                row[len] = bonus[b];
                for (int p = len + 1; p <= S; ++p) row[p] = PLACEHOLDER;
            }
        }
    }
}

// K3: heavy vocab scans, KB blocks per request row, packed atomicMax combine
__global__ __launch_bounds__(256) void k3_scan(
    const float* __restrict__ dp, const float* __restrict__ tp,
    const float* __restrict__ q, const int* __restrict__ scanrow,
    const int* __restrict__ scankind, unsigned long long* __restrict__ packed,
    int V)
{
    const int bq = blockIdx.x / KB, slice = blockIdx.x % KB;
    const int row = scanrow[bq];
    if (row < 0) return;
    const int tid = threadIdx.x;
    __shared__ float s_v[4];
    __shared__ int   s_i[4];

    const int V4 = V >> 2;
    const int c4 = (V4 + KB - 1) / KB;
    const int j0 = slice * c4;
    const int j1 = min(j0 + c4, V4);

    float bv = 0.0f; int bi = 0x7FFFFFFF;   // loses every tie; safe if lane sees no elems
    if (scankind[bq]) {
        const float4* t4 = (const float4*)(tp + (size_t)row * V);
        for (int j = j0 + tid; j < j1; j += 256) {
            const float4 t = t4[j]; const int base = j << 2;
            if (t.x > bv) { bv = t.x; bi = base;     }
            if (t.y > bv) { bv = t.y; bi = base + 1; }
            if (t.z > bv) { bv = t.z; bi = base + 2; }
            if (t.w > bv) { bv = t.w; bi = base + 3; }
        }
        if (slice == KB - 1)
            for (int j = (V4 << 2) + tid; j < V; j += 256) {
                const float tv = tp[(size_t)row * V + j];
                if (tv > bv) { bv = tv; bi = j; }
            }
    } else {
        const float4* t4 = (const float4*)(tp + (size_t)row * V);
        const float4* d4 = (const float4*)(dp + (size_t)row * V);
        const float4* q4 = (const float4*)(q  + (size_t)bq  * V);
        for (int j = j0 + tid; j < j1; j += 256) {
            const float4 t = t4[j], d = d4[j], qq = q4[j];
            const int base = j << 2;
            float r;
            r = fmaxf(t.x - d.x, 0.0f) / qq.x; if (r > bv) { bv = r; bi = base;     }
            r = fmaxf(t.y - d.y, 0.0f) / qq.y; if (r > bv) { bv = r; bi = base + 1; }
            r = fmaxf(t.z - d.z, 0.0f) / qq.z; if (r > bv) { bv = r; bi = base + 2; }
            r = fmaxf(t.w - d.w, 0.0f) / qq.w; if (r > bv) { bv = r; bi = base + 3; }
        }
        if (slice == KB - 1)
            for (int j = (V4 << 2) + tid; j < V; j += 256) {
                const float r = fmaxf(tp[(size_t)row * V + j] - dp[(size_t)row * V + j], 0.0f)
                                / q[(size_t)bq * V + j];
                if (r > bv) { bv = r; bi = j; }
            }
    }
    block_argmax(bv, bi, s_v, s_i);
    if (tid == 0) atomicMax(&packed[bq], pack_vi(bv, bi));
}

// K4: decode winners; greedy assembly (+ rare sequential continuation)
__global__ __launch_bounds__(1024) void k4_finish(
    const float* __restrict__ tp, const int* __restrict__ cu,
    const int* __restrict__ did, const int* __restrict__ bonus,
    const void* __restrict__ grd, const int* __restrict__ scanrow,
    const unsigned long long* __restrict__ packed,
    int* __restrict__ out, int B, int V, int S)
{
    __shared__ int   s_flags[2];
    __shared__ float s_v[16];
    __shared__ int   s_i[16];
    const int b = blockIdx.x, tid = threadIdx.x;
    const bool g = detect_greedy(grd, b, B, s_flags);
    const int start = b ? cu[b - 1] : 0;
    const int len   = cu[b] - start;
    int* row = out + b * (S + 1);

    if (!g) {
        const int sr = scanrow[b];
        if (sr >= 0 && tid == 0) {
            const unsigned long long pk = packed[b];
            row[sr - start] = (int)(0xFFFFFFFFu - (unsigned)(pk & 0xFFFFFFFFull));
        }
        return;
    }
    // greedy: row 0 argmax came from K3
    const unsigned long long pk = packed[b];
    const int tok0 = (int)(0xFFFFFFFFu - (unsigned)(pk & 0xFFFFFFFFull));
    if (tid == 0) row[0] = tok0;
    bool ok = (did[start] == tok0);
    int p = 1;
    const int V4 = V >> 2;
    for (; p < len && ok; ++p) {   // statistically never entered (match prob ~1/V)
        const float4* t4 = (const float4*)(tp + (size_t)(start + p) * V);
        float bv = 0.0f; int bi = 0x7FFFFFFF;
        for (int j = tid; j < V4; j += 1024) {
            const float4 t = t4[j]; const int base = j << 2;
            if (t.x > bv) { bv = t.x; bi = base;     }
            if (t.y > bv) { bv = t.y; bi = base + 1; }
            if (t.z > bv) { bv = t.z; bi = base + 2; }
            if (t.w > bv) { bv = t.w; bi = base + 3; }
        }
        for (int j = (V4 << 2) + tid; j < V; j += 1024) {
            const float tv = tp[(size_t)(start + p) * V + j];
            if (tv > bv) { bv = tv; bi = j; }
        }
        block_argmax(bv, bi, s_v, s_i);
        if (tid == 0) row[p] = bi;
        ok = (did[start + p] == bi);
    }
    if (tid == 0) {
        for (int r = p; r <= S; ++r) row[r] = PLACEHOLDER;
        if (ok) row[len] = bonus[b];
    }
}

extern "C" void kernel_launch(void* const* d_in, const int* in_sizes, int n_in,
                              void* d_out, int out_size, void* d_ws, size_t ws_size,
                              hipStream_t stream) {
    const float* dp  = (const float*)d_in[0];   // draft_probs  [N,V]
    const float* tp  = (const float*)d_in[1];   // target_probs [N,V]
    const float* up  = (const float*)d_in[2];   // uniform_probs [N]
    const float* q   = (const float*)d_in[3];   // q [B,V]
    const int*   cu  = (const int*)d_in[4];     // cu_num_draft_tokens [B]
    const int*   did = (const int*)d_in[5];     // draft_token_ids [N]
    const int*   bon = (const int*)d_in[6];     // bonus_token_ids [B]
    const void*  grd = d_in[7];                 // is_greedy [B]

    const int B = in_sizes[4];
    const int N = in_sizes[5];
    const int V = in_sizes[0] / N;
    const int S = out_size / B - 1;

    int* scanrow  = (int*)d_ws;
    int* scankind = scanrow + B;
    unsigned long long* packed = (unsigned long long*)(scanrow + 2 * B);

    k1_prepass<<<B, 64, 0, stream>>>(dp, tp, up, cu, did, bon, grd,
                                     (int*)d_out, scanrow, scankind, packed, B, V, S);
    k3_scan<<<B * KB, 256, 0, stream>>>(dp, tp, q, scanrow, scankind, packed, V);
    k4_finish<<<B, 1024, 0, stream>>>(tp, cu, did, bon, grd, scanrow, packed,
                                      (int*)d_out, B, V, S);
}